// Round 20
// baseline (172.125 us; speedup 1.0000x reference)
//
#include <hip/hip_runtime.h>
#include <hip/hip_bf16.h>
#include <math.h>

#define NB 8
#define NN 8192
#define ND 1024
#define NH 256
#define NC 2
#define M_ALL (NB * NN)   // 65536 rows
#define BM 128            // block tile rows
#define TPB 64            // tiles per bag
#define NKS 32            // 32 k-steps of 32
#define PSTRIDE 260       // per-tile partial: 256 pooled + m_t + l_t (+pad)

typedef __attribute__((ext_vector_type(8))) short bf16x8;
typedef __attribute__((ext_vector_type(4))) float f32x4;

__device__ inline unsigned short f2bf(float f) {   // RNE float -> bf16 bits
    unsigned int u = __builtin_bit_cast(unsigned int, f);
    u += 0x7FFFu + ((u >> 16) & 1u);
    return (unsigned short)(u >> 16);
}
__device__ inline float bf2f(unsigned short s) {
    unsigned int u = ((unsigned int)s) << 16;
    return __builtin_bit_cast(float, u);
}
__device__ inline unsigned int pk_bf16(float a, float b) {  // low=a, high=b
    __hip_bfloat162 t = __float22bfloat162_rn(float2{a, b});
    unsigned int r;
    __builtin_memcpy(&r, &t, 4);
    return r;
}

__device__ inline float wave_reduce_sum(float v) {
#pragma unroll
    for (int off = 32; off > 0; off >>= 1) v += __shfl_down(v, off, 64);
    return v;
}
__device__ inline float wave_reduce_max(float v) {
#pragma unroll
    for (int off = 32; off > 0; off >>= 1) v = fmaxf(v, __shfl_down(v, off, 64));
    return v;
}

// ---------------------------------------------------------------------------
// Pack Wp into bf16 (RNE), MFMA-B-fragment-contiguous (16x16x32):
// frag (ks 0..31, f = col-frag 0..15), lane l holds
// B[k = ks*32 + (l>>4)*8 + j][col = f*16 + (l&15)], j=0..7 contiguous.
// ---------------------------------------------------------------------------
__global__ void pack_kernel(const float* __restrict__ Wp,
                            unsigned short* __restrict__ hi)
{
    int idx  = blockIdx.x * 256 + threadIdx.x;   // 0..32767
    int lane = idx & 63;
    int f    = (idx >> 6) & 15;
    int t    = idx >> 10;
    int col  = f * 16 + (lane & 15);
    int k0   = t * 32 + (lane >> 4) * 8;
    size_t off = (size_t)idx * 8;
#pragma unroll
    for (int j = 0; j < 8; ++j)
        hi[off + j] = f2bf(Wp[(size_t)(k0 + j) * NH + col]);
}

// ---------------------------------------------------------------------------
// Fused GEMM + SiLU + attention logit + flash-style tile pooling.
// BARRIER-FREE, LDS-FREE K-loop: A fragments loaded DIRECTLY from global
// fp32 (per instr: 16 rows x 128 B contiguous -- L1 serves the 4x same-wr
// reuse within the block), cvt_pk in-register, MFMA. No staging, no
// ds ops, no __syncthreads: 8 waves fully independent; ~320 live blocks
// on 256 CUs + ~190 VGPR give 3-4 unsynchronized waves/SIMD of TLP.
// Dual raw-A and B reg sets: prefetch(ks+1) issued before consume(ks),
// FIFO leaves newest loads in flight (counted waits, never drain).
// Numerics: x RNE-bf16 (in cvt), single bf16 W, fp32 h -- identical to R19.
// ---------------------------------------------------------------------------
__global__ __launch_bounds__(512, 1)
void gemm_kernel(const float* __restrict__ x,
                 const unsigned short* __restrict__ Bhi,
                 const float* __restrict__ bp,
                 const float* __restrict__ Wa,
                 const float* __restrict__ ba,
                 const int* __restrict__ lengths,
                 float* __restrict__ part)
{
    __shared__ float smem[1280];   // epilogue only: a_red 512 | a_vals 128 | redm 8 | bc2 2 | pp 512

    const int tid  = threadIdx.x;
    const int wave = tid >> 6;
    const int lane = tid & 63;
    const int wr = wave >> 2;           // 0..1: 64-row group
    const int wc = wave & 3;            // 0..3: 64-col group
    const int blk = blockIdx.x;
    const size_t row0 = (size_t)blk * BM;

    // ragged early-exit
    const int bag   = blk >> 6;                // 64 tiles per bag
    const int tile  = blk & 63;
    const int lrow0 = tile * BM;
    const int len   = lengths[bag];
    if (lrow0 >= len) return;

    // ---- A direct-load base: lane covers row (lane&15) of each 16-row frag,
    // k-slot (lane>>4)*8. Per instr: 16 rows x 128 B contiguous.
    const float* const xlane = x + (row0 + wr * 64 + (lane & 15)) * ND + (lane >> 4) * 8;

    // ---- B fragment base (frag idx = ks*16 + wc*4 + n; 512 ushorts/frag)
    const unsigned short* bhp = Bhi + ((size_t)(wc * 4) * 64 + lane) * 8;

    float4 rawE[8], rawO[8];            // dual raw A sets (32 VGPR each)
    bf16x8 s0[4], s1[4];                // dual B sets (16 VGPR each)

    auto loadA = [&](int ks, float4* raw) {
#pragma unroll
        for (int mq = 0; mq < 4; ++mq) {
            const float* p = xlane + (size_t)mq * 16 * ND + ks * 32;
            raw[2 * mq]     = *(const float4*)p;
            raw[2 * mq + 1] = *(const float4*)(p + 4);
        }
    };
    auto loadB = [&](int ks, bf16x8* s) {
        const unsigned short* h = bhp + (size_t)ks * 8192;
#pragma unroll
        for (int n = 0; n < 4; ++n) s[n] = *(const bf16x8*)(h + n * 512);
    };

    f32x4 acc[4][4];
#pragma unroll
    for (int m = 0; m < 4; ++m)
#pragma unroll
        for (int n = 0; n < 4; ++n) acc[m][n] = f32x4{0.f, 0.f, 0.f, 0.f};

    auto cvtmfma = [&](const float4* raw, const bf16x8* B) {
        bf16x8 af[4];
#pragma unroll
        for (int mq = 0; mq < 4; ++mq) {
            unsigned int u0 = pk_bf16(raw[2 * mq].x,     raw[2 * mq].y);
            unsigned int u1 = pk_bf16(raw[2 * mq].z,     raw[2 * mq].w);
            unsigned int u2 = pk_bf16(raw[2 * mq + 1].x, raw[2 * mq + 1].y);
            unsigned int u3 = pk_bf16(raw[2 * mq + 1].z, raw[2 * mq + 1].w);
            unsigned int uu[4] = {u0, u1, u2, u3};
            __builtin_memcpy(&af[mq], uu, 16);
        }
        __builtin_amdgcn_s_setprio(1);
#pragma unroll
        for (int n = 0; n < 4; ++n)
#pragma unroll
            for (int mq = 0; mq < 4; ++mq)
                acc[mq][n] = __builtin_amdgcn_mfma_f32_16x16x32_bf16(af[mq], B[n], acc[mq][n], 0, 0, 0);
        __builtin_amdgcn_s_setprio(0);
    };

    // prologue: ks=0 into even sets
    loadA(0, rawE);
    loadB(0, s0);

    for (int ks = 0; ks < NKS; ks += 2) {
        // even k-step: prefetch odd(ks+1), consume even(ks)
        loadA(ks + 1, rawO);
        loadB(ks + 1, s1);
        cvtmfma(rawE, s0);
        // odd k-step: prefetch even(ks+2), consume odd(ks+1)
        if (ks + 2 < NKS) {
            loadA(ks + 2, rawE);
            loadB(ks + 2, s0);
        }
        cvtmfma(rawO, s1);
    }

    // =========== epilogue: SiLU in-register, logits, flash-pool ===========
    float* a_red  = smem;               // [4][128]
    float* a_vals = smem + 512;         // [128]
    float* redm   = smem + 640;         // [8]
    float* bc2    = smem + 648;         // [2]
    float* pp     = smem + 656;         // [2][256]

    const int rg = lane >> 4;
    float bpc[4], wac[4];
#pragma unroll
    for (int n = 0; n < 4; ++n) {
        int col = wc * 64 + n * 16 + (lane & 15);
        bpc[n] = bp[col];
        wac[n] = Wa[col];
    }

    // SiLU (overwrite acc with h, fp32) + per-row attention-logit partials
    float pa[16];
#pragma unroll
    for (int i = 0; i < 16; ++i) pa[i] = 0.f;
#pragma unroll
    for (int m = 0; m < 4; ++m)
#pragma unroll
        for (int n = 0; n < 4; ++n)
#pragma unroll
            for (int j = 0; j < 4; ++j) {
                float v  = acc[m][n][j] + bpc[n];
                float hh = v / (1.f + __expf(-v));
                acc[m][n][j] = hh;
                pa[m * 4 + j] = fmaf(hh, wac[n], pa[m * 4 + j]);
            }
    // reduce pa over the 16 lanes sharing each row
#pragma unroll
    for (int i = 0; i < 16; ++i) {
#pragma unroll
        for (int off = 1; off < 16; off <<= 1)
            pa[i] += __shfl_xor(pa[i], off, 64);
    }
    __syncthreads();          // waves may be at different points; sync before overlay
    if ((lane & 15) == 0) {
#pragma unroll
        for (int m = 0; m < 4; ++m)
#pragma unroll
            for (int j = 0; j < 4; ++j)
                a_red[wc * BM + wr * 64 + m * 16 + rg * 4 + j] = pa[m * 4 + j];
    }
    __syncthreads();
    if (tid < BM) {
        float av = a_red[tid] + a_red[BM + tid] + a_red[2 * BM + tid] + a_red[3 * BM + tid] + ba[0];
        a_vals[tid] = (lrow0 + tid < len) ? av : -3e38f;   // mask invalid rows
    }
    __syncthreads();

    // m_t = max over valid rows
    float mv = (tid < BM) ? a_vals[tid] : -3e38f;
    mv = wave_reduce_max(mv);
    if (lane == 0) redm[wave] = mv;
    __syncthreads();
    if (tid == 0) {
        float m = redm[0];
#pragma unroll
        for (int w = 1; w < 8; ++w) m = fmaxf(m, redm[w]);
        bc2[0] = m;
    }
    __syncthreads();
    const float m_t = bc2[0];

    // l_t = sum exp(a - m_t) over valid rows
    float es = (tid < BM) ? __expf(a_vals[tid] - m_t) : 0.f;
    es = wave_reduce_sum(es);
    if (lane == 0) redm[wave] = es;
    __syncthreads();
    float l_t = 0.f;
    if (tid == 0) {
#pragma unroll
        for (int w = 0; w < 8; ++w) l_t += redm[w];
    }

    // pooled partial: pp[c] = sum_rows exp(a-m_t) * h[row][c]  (h fp32 in acc)
    float ev[16];
    const int rbase = wr * 64 + rg * 4;
#pragma unroll
    for (int m = 0; m < 4; ++m)
#pragma unroll
        for (int j = 0; j < 4; ++j)
            ev[m * 4 + j] = __expf(a_vals[rbase + m * 16 + j] - m_t);
#pragma unroll
    for (int n = 0; n < 4; ++n) {
        float s = 0.f;
#pragma unroll
        for (int m = 0; m < 4; ++m)
#pragma unroll
            for (int j = 0; j < 4; ++j)
                s = fmaf(ev[m * 4 + j], acc[m][n][j], s);
        s += __shfl_xor(s, 16, 64);
        s += __shfl_xor(s, 32, 64);
        if (lane < 16) pp[wr * 256 + wc * 64 + n * 16 + lane] = s;
    }
    __syncthreads();

    const size_t pbase = ((size_t)bag * TPB + tile) * PSTRIDE;
    if (tid < 256) part[pbase + tid] = pp[tid] + pp[256 + tid];
    if (tid == 0) { part[pbase + 256] = m_t; part[pbase + 257] = l_t; }
}

// ---------------------------------------------------------------------------
// final: one block per bag. Flash-combine the per-tile partials, then
// logits = pooled @ Wc + bc.
// ---------------------------------------------------------------------------
__global__ __launch_bounds__(256)
void final_kernel(const float* __restrict__ part, const int* __restrict__ lengths,
                  const float* __restrict__ Wc, const float* __restrict__ bc,
                  float* __restrict__ out)
{
    __shared__ float red0[4], red1[4];
    const int b = blockIdx.x;
    const int c = threadIdx.x;
    const int len = lengths[b];
    int nt = (len + BM - 1) / BM;
    if (nt > TPB) nt = TPB;

    float mg = -3e38f;
    for (int t = 0; t < nt; ++t)
        mg = fmaxf(mg, part[((size_t)b * TPB + t) * PSTRIDE + 256]);

    float W = 0.f, pooled = 0.f;
    for (int t = 0; t < nt; ++t) {
        const size_t pb = ((size_t)b * TPB + t) * PSTRIDE;
        float sc = __expf(part[pb + 256] - mg);
        W      = fmaf(sc, part[pb + 257], W);
        pooled = fmaf(sc, part[pb + c],  pooled);
    }
    pooled /= W;

    const float wc0 = Wc[c * NC + 0], wc1 = Wc[c * NC + 1];
    const int wave = threadIdx.x >> 6, lane = threadIdx.x & 63;
    float l0 = wave_reduce_sum(pooled * wc0);
    float l1 = wave_reduce_sum(pooled * wc1);
    if (lane == 0) { red0[wave] = l0; red1[wave] = l1; }
    __syncthreads();
    if (threadIdx.x == 0) {
        out[b * NC + 0] = red0[0] + red0[1] + red0[2] + red0[3] + bc[0];
        out[b * NC + 1] = red1[0] + red1[1] + red1[2] + red1[3] + bc[1];
    }
}

extern "C" void kernel_launch(void* const* d_in, const int* in_sizes, int n_in,
                              void* d_out, int out_size, void* d_ws, size_t ws_size,
                              hipStream_t stream)
{
    const float* x       = (const float*)d_in[0];
    const int*   lengths = (const int*)d_in[1];
    const float* Wp      = (const float*)d_in[2];
    const float* bp      = (const float*)d_in[3];
    const float* Wa      = (const float*)d_in[4];
    const float* ba      = (const float*)d_in[5];
    const float* Wc      = (const float*)d_in[6];
    const float* bc      = (const float*)d_in[7];
    float* out = (float*)d_out;

    // workspace layout
    unsigned short* whi = (unsigned short*)d_ws;              // 512 KB
    float* part = (float*)(whi + 262144);                     // 8*64*260 f = 532 KB

    pack_kernel<<<128, 256, 0, stream>>>(Wp, whi);
    gemm_kernel<<<M_ALL / BM, 512, 0, stream>>>(x, whi, bp, Wa, ba, lengths, part);
    final_kernel<<<NB, 256, 0, stream>>>(part, lengths, Wc, bc, out);
}

// Round 21
// 97.412 us; speedup vs baseline: 1.7670x; 1.7670x over previous
//
#include <hip/hip_runtime.h>
#include <hip/hip_bf16.h>
#include <math.h>

#define NB 8
#define NN 8192
#define ND 1024
#define NH 256
#define NC 2
#define M_ALL (NB * NN)   // 65536 rows
#define BM 256            // block tile rows
#define BK 128            // K per iteration (4 MFMA k-steps of 32)
#define NT (ND / BK)      // 8 iterations
#define PSTRIDE 260       // per-tile partial: 256 pooled + m_t + l_t (+pad)
#define SMEM_BYTES 131072 // 2 x 64KB bf16 A tiles

typedef __attribute__((ext_vector_type(8))) short bf16x8;
typedef __attribute__((ext_vector_type(4))) float f32x4;

// barrier WITHOUT the compiler's vmcnt(0) drain: LDS ordering only.
#define BARRIER_LGKM() asm volatile("s_waitcnt lgkmcnt(0)\n\ts_barrier" ::: "memory")

__device__ inline unsigned short f2bf(float f) {   // RNE float -> bf16 bits
    unsigned int u = __builtin_bit_cast(unsigned int, f);
    u += 0x7FFFu + ((u >> 16) & 1u);
    return (unsigned short)(u >> 16);
}
__device__ inline float bf2f(unsigned short s) {
    unsigned int u = ((unsigned int)s) << 16;
    return __builtin_bit_cast(float, u);
}
__device__ inline unsigned int pk_bf16(float a, float b) {  // low=a, high=b
    __hip_bfloat162 t = __float22bfloat162_rn(float2{a, b});
    unsigned int r;
    __builtin_memcpy(&r, &t, 4);
    return r;
}

__device__ inline float wave_reduce_sum(float v) {
#pragma unroll
    for (int off = 32; off > 0; off >>= 1) v += __shfl_down(v, off, 64);
    return v;
}
__device__ inline float wave_reduce_max(float v) {
#pragma unroll
    for (int off = 32; off > 0; off >>= 1) v = fmaxf(v, __shfl_down(v, off, 64));
    return v;
}

// ---------------------------------------------------------------------------
// Pack Wp into bf16 (RNE), MFMA-B-fragment-contiguous (16x16x32):
// frag (ks 0..31, f = col-frag 0..15), lane l holds
// B[k = ks*32 + (l>>4)*8 + j][col = f*16 + (l&15)], j=0..7 contiguous.
// ---------------------------------------------------------------------------
__global__ void pack_kernel(const float* __restrict__ Wp,
                            unsigned short* __restrict__ hi)
{
    int idx  = blockIdx.x * 256 + threadIdx.x;   // 0..32767
    int lane = idx & 63;
    int f    = (idx >> 6) & 15;
    int t    = idx >> 10;
    int col  = f * 16 + (lane & 15);
    int k0   = t * 32 + (lane >> 4) * 8;
    size_t off = (size_t)idx * 8;
#pragma unroll
    for (int j = 0; j < 8; ++j)
        hi[off + j] = f2bf(Wp[(size_t)(k0 + j) * NH + col]);
}

// ---------------------------------------------------------------------------
// Fused GEMM + SiLU + attention logit + flash-style tile pooling.
// R19 skeleton with BK 64->128: 8 barrier periods instead of 16 -- the
// per-period fixed costs (lockstep skew, gx vmcnt, B-L2 exposure) amortize
// over 2x MFMA. x staged as two half-tiles through ONE gx[8] set (h0
// consumed after kstep0, h1 after kstep2; each load >=1.2k cyc cover).
// Dual rotating B sets (no per-k-step WAR). Register envelope identical
// to R19 (~228): acc 128 + gx 32 + B 32 + af 16 + addr.
// Numerics identical to R19: x RNE-bf16, single bf16 W, fp32 h pooling.
// ---------------------------------------------------------------------------
__global__ __launch_bounds__(512, 2)
void gemm_kernel(const float* __restrict__ x,
                 const unsigned short* __restrict__ Bhi,
                 const float* __restrict__ bp,
                 const float* __restrict__ Wa,
                 const float* __restrict__ ba,
                 const int* __restrict__ lengths,
                 float* __restrict__ part)
{
    extern __shared__ __align__(16) unsigned char lds_raw[];  // 2 x 64KB A dbuf; epilogue overlay

    const int tid  = threadIdx.x;
    const int wave = tid >> 6;
    const int lane = tid & 63;
    const int wr = wave >> 2;           // 0..1: 128-row group
    const int wc = wave & 3;            // 0..3: 64-col group
    const int blk = blockIdx.x;
    const size_t row0 = (size_t)blk * BM;

    // ragged early-exit
    const int bag   = blk >> 5;                // 32 tiles per bag
    const int tile  = blk & 31;
    const int lrow0 = tile * BM;
    const int len   = lengths[bag];
    if (lrow0 >= len) return;

    // ---- x staging: thread -> row (tid>>1); shalf = tid&1.
    // Per row (128 floats): thread covers chunks {shalf*32, 64+shalf*32}.
    const int srow = tid >> 1;                 // 0..255
    const int shalf = tid & 1;
    const float* xp = x + (row0 + srow) * ND + shalf * 32;
    const int swz = (srow & 7) << 4;
    char* const wrow = (char*)lds_raw + srow * 256;

    float4 gx[8];                              // 32 VGPR, half-tile staging
    auto issueX = [&](int t, int half) {
        const float4* p = (const float4*)(xp + (size_t)t * BK + half * 64);
#pragma unroll
        for (int i = 0; i < 8; ++i) gx[i] = p[i];
    };
    auto dswrite = [&](int buf, int half) {
        char* base = wrow + buf * 65536;
        const int boff = shalf * 64 + half * 128;
#pragma unroll
        for (int q = 0; q < 4; ++q) {
            uint4 w;
            w.x = pk_bf16(gx[2 * q].x,     gx[2 * q].y);
            w.y = pk_bf16(gx[2 * q].z,     gx[2 * q].w);
            w.z = pk_bf16(gx[2 * q + 1].x, gx[2 * q + 1].y);
            w.w = pk_bf16(gx[2 * q + 1].z, gx[2 * q + 1].w);
            *(uint4*)(base + ((boff + q * 16) ^ swz)) = w;
        }
    };

    // ---- B fragment bases (frag idx = kstep*16 + wc*4 + n; 512 ushorts/frag)
    const unsigned short* bhp = Bhi + ((size_t)(wc * 4) * 64 + lane) * 8;

    bf16x8 s0[4], s1[4];                       // dual rotating B sets (32 VGPR)
    auto loadB0 = [&](int ks) {
        const unsigned short* h = bhp + (size_t)ks * 8192;
#pragma unroll
        for (int n = 0; n < 4; ++n) s0[n] = *(const bf16x8*)(h + n * 512);
    };
    auto loadB1 = [&](int ks) {
        const unsigned short* h = bhp + (size_t)ks * 8192;
#pragma unroll
        for (int n = 0; n < 4; ++n) s1[n] = *(const bf16x8*)(h + n * 512);
    };

    // ---- A fragment addressing (row stride 256 B)
    const int arow_l = lane & 15;
    const int akg    = (lane >> 4) * 16;       // byte offset of 8-bf16 k-group

    f32x4 acc[8][4];
#pragma unroll
    for (int m = 0; m < 8; ++m)
#pragma unroll
        for (int n = 0; n < 4; ++n) acc[m][n] = f32x4{0.f, 0.f, 0.f, 0.f};

    auto mfma_ks = [&](int kk, const bf16x8 (&B)[4], const char* ab) {
        __builtin_amdgcn_s_setprio(1);
#pragma unroll
        for (int mm = 0; mm < 2; ++mm) {
            bf16x8 af[4];
#pragma unroll
            for (int q = 0; q < 4; ++q) {
                const int arow = wr * 128 + (mm * 4 + q) * 16 + arow_l;
                af[q] = *(const bf16x8*)(ab + arow * 256 + ((kk * 64 + akg) ^ ((arow & 7) << 4)));
            }
#pragma unroll
            for (int n = 0; n < 4; ++n)
#pragma unroll
                for (int q = 0; q < 4; ++q)
                    acc[mm * 4 + q][n] = __builtin_amdgcn_mfma_f32_16x16x32_bf16(af[q], B[n], acc[mm * 4 + q][n], 0, 0, 0);
        }
        __builtin_amdgcn_s_setprio(0);
    };

    // prologue: tile 0 -> buf0 (both halves); B(0) -> s0; h0(1) in flight
    issueX(0, 0);
    dswrite(0, 0);
    issueX(0, 1);
    dswrite(0, 1);
    loadB0(0);
    issueX(1, 0);          // gx = h0(tile 1)
    BARRIER_LGKM();

    for (int t = 0; t < NT; ++t) {
        const char* ab = (const char*)lds_raw + (t & 1) * 65536;
        const int nxt = (t & 1) ^ 1;
        const int ks0 = 4 * t;
        // kstep0 (consumes s0): prefetch s1(ks0+1)
        loadB1(ks0 + 1);
        mfma_ks(0, s0, ab);
        // stage h0(t+1) (in gx since mid prev iter), then fetch h1(t+1)
        if (t < NT - 1) { dswrite(nxt, 0); issueX(t + 1, 1); }
        // kstep1 (consumes s1): prefetch s0(ks0+2)
        loadB0(ks0 + 2);
        mfma_ks(1, s1, ab);
        // kstep2 (consumes s0): prefetch s1(ks0+3)
        loadB1(ks0 + 3);
        mfma_ks(2, s0, ab);
        // stage h1(t+1) (~2 ksteps of cover), then fetch h0(t+2)
        if (t < NT - 1) { dswrite(nxt, 1); if (t + 2 < NT) issueX(t + 2, 0); }
        // kstep3 (consumes s1): prefetch s0(next iter kstep0)
        if (t < NT - 1) loadB0(ks0 + 4);
        mfma_ks(3, s1, ab);
        if (t < NT - 1) BARRIER_LGKM();
    }

    // =========== epilogue: SiLU in-register, logits, flash-pool ===========
    float* a_red  = (float*)lds_raw;            // [4][256]  4 KB
    float* a_vals = (float*)(lds_raw + 4096);   // [256]     1 KB
    float* redm   = (float*)(lds_raw + 5120);   // [8]
    float* bc2    = (float*)(lds_raw + 5152);   // [2]
    float* pp     = (float*)(lds_raw + 5248);   // [2][256]  2 KB

    const int rg = lane >> 4;
    float bpc[4], wac[4];
#pragma unroll
    for (int n = 0; n < 4; ++n) {
        int col = wc * 64 + n * 16 + (lane & 15);
        bpc[n] = bp[col];
        wac[n] = Wa[col];
    }

    // SiLU (overwrite acc with h, fp32) + per-row attention-logit partials
    float pa[32];
#pragma unroll
    for (int i = 0; i < 32; ++i) pa[i] = 0.f;
#pragma unroll
    for (int m = 0; m < 8; ++m)
#pragma unroll
        for (int n = 0; n < 4; ++n)
#pragma unroll
            for (int j = 0; j < 4; ++j) {
                float v  = acc[m][n][j] + bpc[n];
                float hh = v / (1.f + __expf(-v));
                acc[m][n][j] = hh;
                pa[m * 4 + j] = fmaf(hh, wac[n], pa[m * 4 + j]);
            }
    // reduce pa over the 16 lanes sharing each row
#pragma unroll
    for (int i = 0; i < 32; ++i) {
#pragma unroll
        for (int off = 1; off < 16; off <<= 1)
            pa[i] += __shfl_xor(pa[i], off, 64);
    }
    __syncthreads();          // K-loop LDS reads done before overlay writes
    if ((lane & 15) == 0) {
#pragma unroll
        for (int m = 0; m < 8; ++m)
#pragma unroll
            for (int j = 0; j < 4; ++j)
                a_red[wc * BM + wr * 128 + m * 16 + rg * 4 + j] = pa[m * 4 + j];
    }
    __syncthreads();
    if (tid < BM) {
        float av = a_red[tid] + a_red[BM + tid] + a_red[2 * BM + tid] + a_red[3 * BM + tid] + ba[0];
        a_vals[tid] = (lrow0 + tid < len) ? av : -3e38f;   // mask invalid rows
    }
    __syncthreads();

    // m_t = max over valid rows
    float mv = (tid < BM) ? a_vals[tid] : -3e38f;
    mv = wave_reduce_max(mv);
    if (lane == 0) redm[wave] = mv;
    __syncthreads();
    if (tid == 0) {
        float m = redm[0];
#pragma unroll
        for (int w = 1; w < 8; ++w) m = fmaxf(m, redm[w]);
        bc2[0] = m;
    }
    __syncthreads();
    const float m_t = bc2[0];

    // l_t = sum exp(a - m_t) over valid rows
    float es = (tid < BM) ? __expf(a_vals[tid] - m_t) : 0.f;
    es = wave_reduce_sum(es);
    if (lane == 0) redm[wave] = es;
    __syncthreads();
    float l_t = 0.f;
    if (tid == 0) {
#pragma unroll
        for (int w = 0; w < 8; ++w) l_t += redm[w];
    }

    // pooled partial: pp[c] = sum_rows exp(a-m_t) * h[row][c]  (h fp32 in acc)
    float ev[32];
    const int rbase = wr * 128 + rg * 4;
#pragma unroll
    for (int m = 0; m < 8; ++m)
#pragma unroll
        for (int j = 0; j < 4; ++j)
            ev[m * 4 + j] = __expf(a_vals[rbase + m * 16 + j] - m_t);
#pragma unroll
    for (int n = 0; n < 4; ++n) {
        float s = 0.f;
#pragma unroll
        for (int m = 0; m < 8; ++m)
#pragma unroll
            for (int j = 0; j < 4; ++j)
                s = fmaf(ev[m * 4 + j], acc[m][n][j], s);
        s += __shfl_xor(s, 16, 64);
        s += __shfl_xor(s, 32, 64);
        if (lane < 16) pp[wr * 256 + wc * 64 + n * 16 + lane] = s;
    }
    __syncthreads();

    const size_t pbase = ((size_t)bag * 32 + tile) * PSTRIDE;
    if (tid < BM) part[pbase + tid] = pp[tid] + pp[256 + tid];
    if (tid == 0) { part[pbase + 256] = m_t; part[pbase + 257] = l_t; }
}

// ---------------------------------------------------------------------------
// final: one block per bag. Flash-combine the per-tile partials, then
// logits = pooled @ Wc + bc.
// ---------------------------------------------------------------------------
__global__ __launch_bounds__(256)
void final_kernel(const float* __restrict__ part, const int* __restrict__ lengths,
                  const float* __restrict__ Wc, const float* __restrict__ bc,
                  float* __restrict__ out)
{
    __shared__ float red0[4], red1[4];
    const int b = blockIdx.x;
    const int c = threadIdx.x;
    const int len = lengths[b];
    int nt = (len + BM - 1) / BM;
    if (nt > 32) nt = 32;

    float mg = -3e38f;
    for (int t = 0; t < nt; ++t)
        mg = fmaxf(mg, part[((size_t)b * 32 + t) * PSTRIDE + 256]);

    float W = 0.f, pooled = 0.f;
    for (int t = 0; t < nt; ++t) {
        const size_t pb = ((size_t)b * 32 + t) * PSTRIDE;
        float sc = __expf(part[pb + 256] - mg);
        W      = fmaf(sc, part[pb + 257], W);
        pooled = fmaf(sc, part[pb + c],  pooled);
    }
    pooled /= W;

    const float wc0 = Wc[c * NC + 0], wc1 = Wc[c * NC + 1];
    const int wave = threadIdx.x >> 6, lane = threadIdx.x & 63;
    float l0 = wave_reduce_sum(pooled * wc0);
    float l1 = wave_reduce_sum(pooled * wc1);
    if (lane == 0) { red0[wave] = l0; red1[wave] = l1; }
    __syncthreads();
    if (threadIdx.x == 0) {
        out[b * NC + 0] = red0[0] + red0[1] + red0[2] + red0[3] + bc[0];
        out[b * NC + 1] = red1[0] + red1[1] + red1[2] + red1[3] + bc[1];
    }
}

extern "C" void kernel_launch(void* const* d_in, const int* in_sizes, int n_in,
                              void* d_out, int out_size, void* d_ws, size_t ws_size,
                              hipStream_t stream)
{
    const float* x       = (const float*)d_in[0];
    const int*   lengths = (const int*)d_in[1];
    const float* Wp      = (const float*)d_in[2];
    const float* bp      = (const float*)d_in[3];
    const float* Wa      = (const float*)d_in[4];
    const float* ba      = (const float*)d_in[5];
    const float* Wc      = (const float*)d_in[6];
    const float* bc      = (const float*)d_in[7];
    float* out = (float*)d_out;

    // workspace layout
    unsigned short* whi = (unsigned short*)d_ws;              // 512 KB
    float* part = (float*)(whi + 262144);                     // 8*32*260 f = 260 KB

    static bool attr_set = false;
    if (!attr_set) {
        hipFuncSetAttribute((const void*)gemm_kernel,
                            hipFuncAttributeMaxDynamicSharedMemorySize, SMEM_BYTES);
        attr_set = true;
    }

    pack_kernel<<<128, 256, 0, stream>>>(Wp, whi);
    gemm_kernel<<<M_ALL / BM, 512, SMEM_BYTES, stream>>>(x, whi, bp, Wa, ba, lengths, part);
    final_kernel<<<NB, 256, 0, stream>>>(part, lengths, Wc, bc, out);
}